// Round 17
// baseline (653.960 us; speedup 1.0000x reference)
//
#include <hip/hip_runtime.h>

// ---------------------------------------------------------------------------
// E89 ResidualStateCell.
// Precision: k,v,decay (feed the recurrence) via split-bf16 (hi+lo) MFMA ->
// fp32; q,Sq,Wout (read-out only) via fp16 MFMA. Scan fp32 with fast tanh.
// Scan: 512 thr/bh (16 lanes/col x 2 elems), 4-deep LDS ring CH=32, counted
// vmcnt(4), inline-asm ds_read groups w/ lgkmcnt(13), delayed-o dual DPP
// reduction (single asm block of fused v_add_f32_dpp with explicit s_nop
// hazard guards -- R15 lesson: separate asm statements let the compiler
// emit DPP back-to-back, violating the 2-wait-state VALU->DPP hazard),
// LDS-buffered Sq flushed by wave 6.
// GEMMs: XCD-aware bijective block swizzle (T1) for L2 panel locality.
// Dispatch chain: megacast -> q-gemm -> fused k/decay/v proj -> scan ->
// out-gemm (5 launches).
// Layout: k,v,q transposed [B][H][T][NS], decay [B][H][T].
// Memory: ws ~171 MB. q fp16 + decay live in d_out head (dead before the
// final out-GEMM overwrites it). x-fp16 aliases vf head; Sq aliases xh/xl.
// ---------------------------------------------------------------------------

typedef __attribute__((ext_vector_type(8))) __bf16 bf16x8;
typedef __attribute__((ext_vector_type(8))) _Float16 f16x8;
typedef __attribute__((ext_vector_type(4))) float f32x4;
typedef __attribute__((ext_vector_type(2))) float f32x2;

#define T_LEN 2048
#define BB 4
#define HH 56
#define NS 32
#define DIM 1024
#define KD 1792            // H*NS
#define MROWS 8192         // T_LEN*BB
#define CH 32              // scan chunk (steps)
#define NCHUNK (T_LEN / CH)

#define VMCNT(N) asm volatile("s_waitcnt vmcnt(" #N ")" ::: "memory")
#define LGKM(N)  asm volatile("s_waitcnt lgkmcnt(" #N ")" ::: "memory")
#define SB       __builtin_amdgcn_sched_barrier(0)

__device__ __forceinline__ float bf2f(unsigned short u) {
    return __uint_as_float(((unsigned int)u) << 16);
}
__device__ __forceinline__ unsigned short f2bf(float f) {
    unsigned int u = __float_as_uint(f);
    u += 0x7fffu + ((u >> 16) & 1u);          // round-to-nearest-even
    return (unsigned short)(u >> 16);
}
__device__ __forceinline__ unsigned short f2h(float f) {
    union { _Float16 h; unsigned short u; } cv;
    cv.h = (_Float16)f;                       // RNE
    return cv.u;
}
__device__ __forceinline__ float h2f(unsigned short u) {
    union { unsigned short u; _Float16 h; } cv;
    cv.u = u;
    return (float)cv.h;
}

// tanh via v_exp_f32 (2^x): tanh(x) = 1 - 2/(1+2^(2*log2e*x))
__device__ __forceinline__ float tanh_fast(float x) {
    float e = __builtin_amdgcn_exp2f(x * 2.885390081777927f);
    float r = __builtin_amdgcn_rcpf(e + 1.0f);
    return fmaf(-2.0f, r, 1.0f);
}

// Sum across each aligned group of 16 lanes, pure-VALU DPP butterfly
// (builtin form: compiler inserts DPP hazard nops).
__device__ __forceinline__ float dpp_sum16(float x) {
    int t;
    t = __builtin_amdgcn_update_dpp(0, __float_as_int(x), 0xB1, 0xf, 0xf, true);
    x += __int_as_float(t);
    t = __builtin_amdgcn_update_dpp(0, __float_as_int(x), 0x4E, 0xf, 0xf, true);
    x += __int_as_float(t);
    t = __builtin_amdgcn_update_dpp(0, __float_as_int(x), 0x141, 0xf, 0xf, true);
    x += __int_as_float(t);
    t = __builtin_amdgcn_update_dpp(0, __float_as_int(x), 0x140, 0xf, 0xf, true);
    x += __int_as_float(t);
    return x;
}

// Dual 16-lane sum: two independent trees, fused v_add_f32_dpp in ONE asm
// block with explicit s_nop hazard guards (gfx9: VALU write -> DPP read of
// that VGPR needs 2 wait states; s_nop 1 = 2 states, and the interleaved
// partner add provides an additional slot). Same add order as dpp_sum16.
__device__ __forceinline__ f32x2 dpp_sum16x2(float a, float b) {
    asm volatile(
        "s_nop 1\n\t"
        "v_add_f32_dpp %0, %0, %0 quad_perm:[1,0,3,2] row_mask:0xf bank_mask:0xf\n\t"
        "v_add_f32_dpp %1, %1, %1 quad_perm:[1,0,3,2] row_mask:0xf bank_mask:0xf\n\t"
        "s_nop 1\n\t"
        "v_add_f32_dpp %0, %0, %0 quad_perm:[2,3,0,1] row_mask:0xf bank_mask:0xf\n\t"
        "v_add_f32_dpp %1, %1, %1 quad_perm:[2,3,0,1] row_mask:0xf bank_mask:0xf\n\t"
        "s_nop 1\n\t"
        "v_add_f32_dpp %0, %0, %0 row_half_mirror row_mask:0xf bank_mask:0xf\n\t"
        "v_add_f32_dpp %1, %1, %1 row_half_mirror row_mask:0xf bank_mask:0xf\n\t"
        "s_nop 1\n\t"
        "v_add_f32_dpp %0, %0, %0 row_mirror row_mask:0xf bank_mask:0xf\n\t"
        "v_add_f32_dpp %1, %1, %1 row_mirror row_mask:0xf bank_mask:0xf\n\t"
        "s_nop 1"
        : "+v"(a), "+v"(b));
    return (f32x2){a, b};
}

__device__ __forceinline__ void gload_lds16(const void* g, void* l) {
    __builtin_amdgcn_global_load_lds(
        (const __attribute__((address_space(1))) unsigned int*)g,
        (__attribute__((address_space(3))) unsigned int*)l, 16, 0, 0);
}
__device__ __forceinline__ void gload_lds4(const void* g, void* l) {
    __builtin_amdgcn_global_load_lds(
        (const __attribute__((address_space(1))) unsigned int*)g,
        (__attribute__((address_space(3))) unsigned int*)l, 4, 0, 0);
}

// LDS byte offset of a generic pointer to __shared__ memory.
__device__ __forceinline__ unsigned lds_off(const void* p) {
    return (unsigned)(unsigned long long)
        (const __attribute__((address_space(3))) char*)p;
}

// Inline-asm LDS reads (opaque to the compiler: cannot be sunk/reordered).
template <int OFF>
__device__ __forceinline__ f32x4 dsr128(unsigned a) {
    f32x4 r;
    asm volatile("ds_read_b128 %0, %1 offset:%2" : "=v"(r) : "v"(a), "n"(OFF));
    return r;
}
template <int OFF>
__device__ __forceinline__ f32x2 dsr64f(unsigned a) {
    f32x2 r;
    asm volatile("ds_read_b64 %0, %1 offset:%2" : "=v"(r) : "v"(a), "n"(OFF));
    return r;
}
template <int OFF>
__device__ __forceinline__ unsigned dsr32u(unsigned a) {
    unsigned r;
    asm volatile("ds_read_b32 %0, %1 offset:%2" : "=v"(r) : "v"(a), "n"(OFF));
    return r;
}
template <int OFF>
__device__ __forceinline__ float dsr32f(unsigned a) {
    float r;
    asm volatile("ds_read_b32 %0, %1 offset:%2" : "=v"(r) : "v"(a), "n"(OFF));
    return r;
}

// XCD-aware bijective block swizzle (nwg divisible by 8).
__device__ __forceinline__ int xcd_swz(int bid, int nwg) {
    return (bid & 7) * (nwg >> 3) + (bid >> 3);
}

// ---------------------------------------------------------------------------
// Megacast: all input casts in one launch. Each thread handles 8 elements.
// ---------------------------------------------------------------------------
__device__ __forceinline__ void do_split8(const float* in, unsigned short* hi,
                                          unsigned short* lo, int i) {
    const float4* p = (const float4*)in + (size_t)i * 2;
    float4 a = p[0], b = p[1];
    float xs[8] = {a.x, a.y, a.z, a.w, b.x, b.y, b.z, b.w};
    unsigned int ho[4], lv[4];
#pragma unroll
    for (int c = 0; c < 4; ++c) {
        unsigned short h0 = f2bf(xs[2 * c]);
        unsigned short h1 = f2bf(xs[2 * c + 1]);
        unsigned short l0 = f2bf(xs[2 * c] - bf2f(h0));
        unsigned short l1 = f2bf(xs[2 * c + 1] - bf2f(h1));
        ho[c] = (unsigned int)h0 | ((unsigned int)h1 << 16);
        lv[c] = (unsigned int)l0 | ((unsigned int)l1 << 16);
    }
    ((uint4*)hi)[i] = (uint4){ho[0], ho[1], ho[2], ho[3]};
    ((uint4*)lo)[i] = (uint4){lv[0], lv[1], lv[2], lv[3]};
}
__device__ __forceinline__ void do_half8(const float* in, unsigned short* out, int i) {
    const float4* p = (const float4*)in + (size_t)i * 2;
    float4 a = p[0], b = p[1];
    uint4 o;
    o.x = (unsigned int)f2h(a.x) | ((unsigned int)f2h(a.y) << 16);
    o.y = (unsigned int)f2h(a.z) | ((unsigned int)f2h(a.w) << 16);
    o.z = (unsigned int)f2h(b.x) | ((unsigned int)f2h(b.y) << 16);
    o.w = (unsigned int)f2h(b.z) | ((unsigned int)f2h(b.w) << 16);
    ((uint4*)out)[i] = o;
}

__global__ void megacast_kernel(
    const float* __restrict__ x, unsigned short* __restrict__ xh,
    unsigned short* __restrict__ xl, unsigned short* __restrict__ xf16,
    const float* __restrict__ Wk, unsigned short* __restrict__ Wkh,
    unsigned short* __restrict__ Wkl,
    const float* __restrict__ Wv, unsigned short* __restrict__ Wvh,
    unsigned short* __restrict__ Wvl,
    const float* __restrict__ Wa, unsigned short* __restrict__ Wah,
    unsigned short* __restrict__ Wal,
    const float* __restrict__ Wq, unsigned short* __restrict__ Wqh16,
    const float* __restrict__ Wout, unsigned short* __restrict__ Woh) {
    int i = blockIdx.x * blockDim.x + threadIdx.x;
    const int N0 = MROWS * DIM / 8;            // x
    const int N1 = KD * DIM / 8;               // Wk/Wv/Wq/Wout
    const int N3 = HH * DIM / 8;               // Wa
    if (i < N0) {
        const float4* p = (const float4*)x + (size_t)i * 2;
        float4 a = p[0], b = p[1];
        float xs[8] = {a.x, a.y, a.z, a.w, b.x, b.y, b.z, b.w};
        unsigned int ho[4], lv[4], hv[4];
#pragma unroll
        for (int c = 0; c < 4; ++c) {
            unsigned short h0 = f2bf(xs[2 * c]);
            unsigned short h1 = f2bf(xs[2 * c + 1]);
            unsigned short l0 = f2bf(xs[2 * c] - bf2f(h0));
            unsigned short l1 = f2bf(xs[2 * c + 1] - bf2f(h1));
            ho[c] = (unsigned int)h0 | ((unsigned int)h1 << 16);
            lv[c] = (unsigned int)l0 | ((unsigned int)l1 << 16);
            hv[c] = (unsigned int)f2h(xs[2 * c]) |
                    ((unsigned int)f2h(xs[2 * c + 1]) << 16);
        }
        ((uint4*)xh)[i]   = (uint4){ho[0], ho[1], ho[2], ho[3]};
        ((uint4*)xl)[i]   = (uint4){lv[0], lv[1], lv[2], lv[3]};
        ((uint4*)xf16)[i] = (uint4){hv[0], hv[1], hv[2], hv[3]};
        return;
    }
    i -= N0;
    if (i < N1) { do_split8(Wk, Wkh, Wkl, i); return; }
    i -= N1;
    if (i < N1) { do_split8(Wv, Wvh, Wvl, i); return; }
    i -= N1;
    if (i < N3) { do_split8(Wa, Wah, Wal, i); return; }
    i -= N3;
    if (i < N1) { do_half8(Wq, Wqh16, i); return; }
    i -= N1;
    if (i < N1) { do_half8(Wout, Woh, i); }
}
#define MEGACAST_ITEMS (MROWS * DIM / 8 + 4 * (KD * DIM / 8) + HH * DIM / 8)

// ---------------------------------------------------------------------------
// Split MFMA GEMM core: Y[m,n] = sum_k A[m,k]*B[n,k], A=Ah+Al, B=Bh+Bl.
// 128x128 tile, BK=32, 256 threads = 4 waves (2x2), 16x16x32 bf16 MFMA x3.
// ---------------------------------------------------------------------------
__device__ __forceinline__ void gemm_split(
    const unsigned short* __restrict__ Ah, const unsigned short* __restrict__ Al,
    const unsigned short* __restrict__ Bh, const unsigned short* __restrict__ Bl,
    int m0, int n0, int K, int bmax,
    unsigned short* AsH, unsigned short* AsL,
    unsigned short* BsH, unsigned short* BsL,
    f32x4 (&acc)[4][4]) {
    const int tid  = threadIdx.x;
    const int lane = tid & 63;
    const int wave = tid >> 6;
    const int wm = wave >> 1, wn = wave & 1;
    const int lr = lane & 15, lkb = lane >> 4;

#pragma unroll
    for (int fr = 0; fr < 4; ++fr)
#pragma unroll
        for (int fc = 0; fc < 4; ++fc) acc[fr][fc] = (f32x4){0.f, 0.f, 0.f, 0.f};

    auto stage = [&](int kt) {
#pragma unroll
        for (int c = 0; c < 2; ++c) {
            int i = c * 256 + tid;
            int r = i >> 2, kk = (i & 3) << 3;
            size_t ao = (size_t)(m0 + r) * K + kt + kk;
            int br = n0 + r; if (br > bmax) br = bmax;
            size_t bo = (size_t)br * K + kt + kk;
            gload_lds16(Ah + ao, AsH + i * 8);
            gload_lds16(Al + ao, AsL + i * 8);
            gload_lds16(Bh + bo, BsH + i * 8);
            gload_lds16(Bl + bo, BsL + i * 8);
        }
    };

    stage(0);
    const int nk = K >> 5;
    for (int t = 0; t < nk; ++t) {
        __syncthreads();                       // drains vmcnt -> LDS tiles ready
        bf16x8 ah[4], al[4], bh[4], bl[4];
#pragma unroll
        for (int f = 0; f < 4; ++f) {
            int ai = (wm * 64 + f * 16 + lr) * 32 + lkb * 8;
            int bi = (wn * 64 + f * 16 + lr) * 32 + lkb * 8;
            ah[f] = *(const bf16x8*)(AsH + ai);
            al[f] = *(const bf16x8*)(AsL + ai);
            bh[f] = *(const bf16x8*)(BsH + bi);
            bl[f] = *(const bf16x8*)(BsL + bi);
        }
#pragma unroll
        for (int fr = 0; fr < 4; ++fr)
#pragma unroll
            for (int fc = 0; fc < 4; ++fc) {
                acc[fr][fc] = __builtin_amdgcn_mfma_f32_16x16x32_bf16(
                    ah[fr], bh[fc], acc[fr][fc], 0, 0, 0);
                acc[fr][fc] = __builtin_amdgcn_mfma_f32_16x16x32_bf16(
                    ah[fr], bl[fc], acc[fr][fc], 0, 0, 0);
                acc[fr][fc] = __builtin_amdgcn_mfma_f32_16x16x32_bf16(
                    al[fr], bh[fc], acc[fr][fc], 0, 0, 0);
            }
        __syncthreads();                       // all waves done reading LDS
        if (t + 1 < nk) stage((t + 1) << 5);
    }
}

// ---------------------------------------------------------------------------
// Fused k/decay/v projection.  Row m = t*BB + b.  XCD-swizzled grid.
// tile 0..13 : k  (silu + fused l2norm) -> fp32 kf  [B][H][T][NS]
// tile 14    : decay                    -> fp32 decayb [B][H][T]
// tile 15..28: v  (silu)                -> fp32 vf  [B][H][T][NS]
// ---------------------------------------------------------------------------
__global__ __launch_bounds__(256) void kv_proj_kernel(
    const unsigned short* __restrict__ xh, const unsigned short* __restrict__ xl,
    const unsigned short* __restrict__ Wkh, const unsigned short* __restrict__ Wkl,
    const unsigned short* __restrict__ Wvh, const unsigned short* __restrict__ Wvl,
    const unsigned short* __restrict__ Wah, const unsigned short* __restrict__ Wal,
    const float* __restrict__ A_log, const float* __restrict__ dt_bias,
    float* __restrict__ kf, float* __restrict__ vf,
    float* __restrict__ decayb) {
    __shared__ __align__(16) unsigned short AsH[128 * 32];
    __shared__ __align__(16) unsigned short AsL[128 * 32];
    __shared__ __align__(16) unsigned short BsH[128 * 32];
    __shared__ __align__(16) unsigned short BsL[128 * 32];

    int bid = blockIdx.y * gridDim.x + blockIdx.x;
    int swz = xcd_swz(bid, gridDim.x * gridDim.y);
    const int tile = swz % gridDim.x;          // 0..28
    const int ytile = swz / gridDim.x;         // 0..63

    int mode; const unsigned short *Bh, *Bl; int n0;
    if (tile < 14)       { mode = 0; Bh = Wkh; Bl = Wkl; n0 = tile * 128; }
    else if (tile == 14) { mode = 1; Bh = Wah; Bl = Wal; n0 = 0; }
    else                 { mode = 2; Bh = Wvh; Bl = Wvl; n0 = (tile - 15) * 128; }
    int m0 = ytile * 128;
    int bmax = (mode == 1) ? (HH - 1) : (KD - 1);

    f32x4 acc[4][4];
    gemm_split(xh, xl, Bh, Bl, m0, n0, DIM, bmax, AsH, AsL, BsH, BsL, acc);

    const int lane = threadIdx.x & 63, wave = threadIdx.x >> 6;
    const int wm = wave >> 1, wn = wave & 1, lr = lane & 15, lkb = lane >> 4;

    if (mode == 1) {
#pragma unroll
        for (int fr = 0; fr < 4; ++fr)
#pragma unroll
            for (int fc = 0; fc < 4; ++fc)
#pragma unroll
                for (int v = 0; v < 4; ++v) {
                    int m = m0 + wm * 64 + fr * 16 + lkb * 4 + v;
                    int n = n0 + wn * 64 + fc * 16 + lr;
                    int t = m >> 2, b = m & 3;
                    if (n < HH) {
                        float z = acc[fr][fc][v] + dt_bias[n];
                        float sp = (z > 20.f) ? z : log1pf(__expf(z));
                        decayb[((size_t)(b * HH + n)) * T_LEN + t] =
                            __expf(-__expf(A_log[n]) * sp);
                    }
                }
        return;
    }

    if (mode == 0) {
        // k: silu + fused l2norm over each head's 32 columns.
#pragma unroll
        for (int fr = 0; fr < 4; ++fr)
#pragma unroll
            for (int hc = 0; hc < 2; ++hc)
#pragma unroll
                for (int v = 0; v < 4; ++v) {
                    float yA = acc[fr][2 * hc][v];
                    float yB = acc[fr][2 * hc + 1][v];
                    float sA = yA / (1.f + __expf(-yA));
                    float sB = yB / (1.f + __expf(-yB));
                    float ss = fmaf(sA, sA, sB * sB);
                    ss = dpp_sum16(ss);            // sum over the head's 32 cols
                    float sc = 1.f / fmaxf(sqrtf(ss), 1e-12f);
                    int m = m0 + wm * 64 + fr * 16 + lkb * 4 + v;
                    int t = m >> 2, b = m & 3;
                    int h = ((n0 + wn * 64) >> 5) + hc;
                    size_t ro = (((size_t)(b * HH + h)) * T_LEN + t) * NS;
                    kf[ro + lr]      = sA * sc;
                    kf[ro + lr + 16] = sB * sc;
                }
    } else {
        // v: silu only
#pragma unroll
        for (int fr = 0; fr < 4; ++fr)
#pragma unroll
            for (int fc = 0; fc < 4; ++fc)
#pragma unroll
                for (int v = 0; v < 4; ++v) {
                    int m = m0 + wm * 64 + fr * 16 + lkb * 4 + v;
                    int n = n0 + wn * 64 + fc * 16 + lr;
                    int t = m >> 2, b = m & 3;
                    int h = n >> 5, i = n & 31;
                    float y = acc[fr][fc][v];
                    float s = y / (1.f + __expf(-y));
                    vf[(((size_t)(b * HH + h)) * T_LEN + t) * NS + i] = s;
                }
    }
}

// ---------------------------------------------------------------------------
// q projection, single fp16 MFMA (q is read-out-only): q = l2norm(silu(x@Wq^T)),
// fp16 store at [B][H][T][NS].  XCD-swizzled grid.
// ---------------------------------------------------------------------------
__global__ __launch_bounds__(256) void q_gemm_f16_kernel(
    const unsigned short* __restrict__ xf, const unsigned short* __restrict__ Wqf,
    unsigned short* __restrict__ dstH) {
    __shared__ __align__(16) unsigned short As[128 * 32];
    __shared__ __align__(16) unsigned short Bs[128 * 32];

    int bid = blockIdx.y * gridDim.x + blockIdx.x;
    int swz = xcd_swz(bid, gridDim.x * gridDim.y);
    int m0 = (swz / gridDim.x) * 128, n0 = (swz % gridDim.x) * 128;

    const int tid  = threadIdx.x;
    const int lane = tid & 63;
    const int wave = tid >> 6;
    const int wm = wave >> 1, wn = wave & 1;
    const int lr = lane & 15, lkb = lane >> 4;

    f32x4 acc[4][4];
#pragma unroll
    for (int fr = 0; fr < 4; ++fr)
#pragma unroll
        for (int fc = 0; fc < 4; ++fc) acc[fr][fc] = (f32x4){0.f, 0.f, 0.f, 0.f};

    auto stage = [&](int kt) {
#pragma unroll
        for (int c = 0; c < 2; ++c) {
            int i = c * 256 + tid;
            int r = i >> 2, kk = (i & 3) << 3;
            gload_lds16(xf + (size_t)(m0 + r) * DIM + kt + kk, As + i * 8);
            gload_lds16(Wqf + (size_t)(n0 + r) * DIM + kt + kk, Bs + i * 8);
        }
    };

    stage(0);
    const int nk = DIM >> 5;
    for (int t = 0; t < nk; ++t) {
        __syncthreads();
        f16x8 af[4], bf[4];
#pragma unroll
        for (int f = 0; f < 4; ++f) {
            af[f] = *(const f16x8*)(As + (wm * 64 + f * 16 + lr) * 32 + lkb * 8);
            bf[f] = *(const f16x8*)(Bs + (wn * 64 + f * 16 + lr) * 32 + lkb * 8);
        }
#pragma unroll
        for (int fr = 0; fr < 4; ++fr)
#pragma unroll
            for (int fc = 0; fc < 4; ++fc)
                acc[fr][fc] = __builtin_amdgcn_mfma_f32_16x16x32_f16(
                    af[fr], bf[fc], acc[fr][fc], 0, 0, 0);
        __syncthreads();
        if (t + 1 < nk) stage((t + 1) << 5);
    }

#pragma unroll
    for (int fr = 0; fr < 4; ++fr)
#pragma unroll
        for (int hc = 0; hc < 2; ++hc)
#pragma unroll
            for (int v = 0; v < 4; ++v) {
                float yA = acc[fr][2 * hc][v];
                float yB = acc[fr][2 * hc + 1][v];
                float sA = yA / (1.f + __expf(-yA));
                float sB = yB / (1.f + __expf(-yB));
                float ss = fmaf(sA, sA, sB * sB);
                ss = dpp_sum16(ss);
                float sc = 1.f / fmaxf(sqrtf(ss), 1e-12f);
                int m = m0 + wm * 64 + fr * 16 + lkb * 4 + v;
                int t = m >> 2, b = m & 3;
                int h = ((n0 + wn * 64) >> 5) + hc;
                size_t ro = (((size_t)(b * HH + h)) * T_LEN + t) * NS;
                dstH[ro + lr]      = f2h(sA * sc);
                dstH[ro + lr + 16] = f2h(sB * sc);
            }
}

// ---------------------------------------------------------------------------
// Output GEMM (fp16): out = Sq @ Wout^T, f32 store.  XCD-swizzled grid.
// ---------------------------------------------------------------------------
__global__ __launch_bounds__(256) void out_gemm_kernel(
    const unsigned short* __restrict__ Sq, const unsigned short* __restrict__ Wo,
    float* __restrict__ out) {
    __shared__ __align__(16) unsigned short As[128 * 32];
    __shared__ __align__(16) unsigned short Bs[128 * 32];

    int bid = blockIdx.y * gridDim.x + blockIdx.x;
    int swz = xcd_swz(bid, gridDim.x * gridDim.y);
    int m0 = (swz / gridDim.x) * 128, n0 = (swz % gridDim.x) * 128;

    const int tid  = threadIdx.x;
    const int lane = tid & 63;
    const int wave = tid >> 6;
    const int wm = wave >> 1, wn = wave & 1;
    const int lr = lane & 15, lkb = lane >> 4;

    f32x4 acc[4][4];
#pragma unroll
    for (int fr = 0; fr < 4; ++fr)
#pragma unroll
        for (int fc = 0; fc < 4; ++fc) acc[fr][fc] = (f32x4){0.f, 0.f, 0.f, 0.f};

    auto stage = [&](int kt) {
#pragma unroll
        for (int c = 0; c < 2; ++c) {
            int i = c * 256 + tid;
            int r = i >> 2, kk = (i & 3) << 3;
            gload_lds16(Sq + (size_t)(m0 + r) * KD + kt + kk, As + i * 8);
            gload_lds16(Wo + (size_t)(n0 + r) * KD + kt + kk, Bs + i * 8);
        }
    };

    stage(0);
    const int nk = KD >> 5;
    for (int t = 0; t < nk; ++t) {
        __syncthreads();
        f16x8 af[4], bf[4];
#pragma unroll
        for (int f = 0; f < 4; ++f) {
            af[f] = *(const f16x8*)(As + (wm * 64 + f * 16 + lr) * 32 + lkb * 8);
            bf[f] = *(const f16x8*)(Bs + (wn * 64 + f * 16 + lr) * 32 + lkb * 8);
        }
#pragma unroll
        for (int fr = 0; fr < 4; ++fr)
#pragma unroll
            for (int fc = 0; fc < 4; ++fc)
                acc[fr][fc] = __builtin_amdgcn_mfma_f32_16x16x32_f16(
                    af[fr], bf[fc], acc[fr][fc], 0, 0, 0);
        __syncthreads();
        if (t + 1 < nk) stage((t + 1) << 5);
    }

#pragma unroll
    for (int fr = 0; fr < 4; ++fr)
#pragma unroll
        for (int fc = 0; fc < 4; ++fc)
#pragma unroll
            for (int v = 0; v < 4; ++v) {
                int m = m0 + wm * 64 + fr * 16 + lkb * 4 + v;
                int n = n0 + wn * 64 + fc * 16 + lr;
                out[(size_t)m * DIM + n] = acc[fr][fc][v];
            }
}

// ---------------------------------------------------------------------------
// Sequential scan: 512 threads (8 waves) per (b,h); 16 lanes/col x 2 elems.
// CH=32 chunks, 4-deep LDS ring staged 2 ahead (waves 0-5, counted VMCNT(4));
// in-chunk 4-step groups via asm ds_read + lgkmcnt(13); delayed-o dual DPP
// reduction (fused, hazard-guarded); Sq buffered in obuf, flushed by wave 6.
// ---------------------------------------------------------------------------
__global__ __launch_bounds__(512, 1) void scan_kernel(
    const float* __restrict__ kf, const unsigned short* __restrict__ qh,
    const float* __restrict__ vf, const float* __restrict__ decayb,
    const float* __restrict__ S0, unsigned short* __restrict__ Sq,
    float* __restrict__ Sout) {
    __shared__ __align__(16) float          kbuf[4][CH][NS];   // 16 KB
    __shared__ __align__(16) float          vbuf[4][CH][NS];   // 16 KB
    __shared__ __align__(16) unsigned short qbuf[4][CH][NS];   // 8 KB
    __shared__ __align__(16) float          dbuf[4][64];       // 1 KB
    __shared__ __align__(16) unsigned short obuf[4][CH][NS];   // 8 KB

    const int bh = blockIdx.x;                 // 0..223  (= b*HH + h)
    const int b = bh / HH, h = bh - b * HH;
    const int tid = threadIdx.x;
    const int lane = tid & 63, wave = tid >> 6;
    const int col = tid >> 4;                  // 0..31 (column j)
    const int ii  = tid & 15;                  // 0..15 (lane within column)
    const int i0  = ii * 2;                    // state elements i0, i0+1

    const float* Sp = S0 + (size_t)bh * NS * NS;
    float s0 = Sp[(i0 + 0) * NS + col];
    float s1 = Sp[(i0 + 1) * NS + col];

    const size_t base  = (size_t)bh * T_LEN * NS;
    const size_t dbase = (size_t)bh * T_LEN;
    const size_t cbcol = (size_t)h * NS;       // Sq column base

    // per-lane LDS base offsets (slot 0)
    const unsigned kb0 = lds_off(&kbuf[0][0][0]) + (unsigned)i0 * 4;
    const unsigned qb0 = lds_off(&qbuf[0][0][0]) + (unsigned)i0 * 2;
    const unsigned vb0 = lds_off(&vbuf[0][0][0]) + (unsigned)col * 4;
    const unsigned db0 = lds_off(&dbuf[0][0]);

    // Wave-specialized chunk staging (CH=32): waves 0-5, <=2 gload each.
    auto stage = [&](int c) {
        int s = c & 3;
        if (wave == 0) {
            const float* src = kf + base + (size_t)c * (CH * NS);
            gload_lds16(src + lane * 4,       &kbuf[s][0][0] + lane * 4);
            gload_lds16(src + 256 + lane * 4, &kbuf[s][8][0] + lane * 4);
        } else if (wave == 1) {
            const float* src = kf + base + (size_t)c * (CH * NS);
            gload_lds16(src + 512 + lane * 4, &kbuf[s][16][0] + lane * 4);
            gload_lds16(src + 768 + lane * 4, &kbuf[s][24][0] + lane * 4);
        } else if (wave == 2) {
            const float* src = vf + base + (size_t)c * (CH * NS);
            gload_lds16(src + lane * 4,       &vbuf[s][0][0] + lane * 4);
            gload_lds16(src + 256 + lane * 4, &vbuf[s][8][0] + lane * 4);
        } else if (wave == 3) {
            const float* src = vf + base + (size_t)c * (CH * NS);
            gload_lds16(src + 512 + lane * 4, &vbuf[s][16][0] + lane * 4);
            gload_lds16(src + 768 + lane * 4, &vbuf[s][24][0] + lane * 4);
        } else if (wave == 4) {
            const unsigned short* src = qh + base + (size_t)c * (CH * NS);
            gload_lds16(src + lane * 8,       &qbuf[s][0][0] + lane * 8);
            gload_lds16(src + 512 + lane * 8, &qbuf[s][16][0] + lane * 8);
        } else if (wave == 5) {
            gload_lds4(decayb + dbase + (size_t)c * CH + lane,
                       &dbuf[s][0] + lane);    // tail lanes: junk, unused
        }
    };

    // Flush chunk cc's o values (obuf slot cc&3) to Sq: 32 rows x 64B.
    auto flush = [&](int cc) {
#pragma unroll
        for (int kk = 0; kk < 2; ++kk) {
            int row = kk * 16 + (lane >> 2);
            int seg = (lane & 3) * 8;
            uint4 dv = *(const uint4*)(&obuf[cc & 3][row][seg]);
            size_t go = ((size_t)(cc * CH + row) * BB + b) * KD + cbcol + seg;
            *(uint4*)(Sq + go) = dv;
        }
    };

    stage(0);
    stage(1);
    VMCNT(0);
    __builtin_amdgcn_s_barrier();

    float o_pend = 0.f;                        // un-reduced o of previous step

    for (int c = 0; c < NCHUNK; ++c) {
        if (c + 2 < NCHUNK) stage(c + 2);
        // Staging waves: outstanding = stage(c+1)[<=2] + stage(c+2)[<=2] = 4
        // -> VMCNT(4) drains stage(c). Compute-only waves: no global ops.
        if (wave < 6) { VMCNT(4); }
        __builtin_amdgcn_s_barrier();
        SB;
        if (wave == 6 && c >= 2) flush(c - 2);

        const int s = c & 3;
        const unsigned kb = kb0 + (unsigned)s * (CH * NS * 4);
        const unsigned qb = qb0 + (unsigned)s * (CH * NS * 2);
        const unsigned vb = vb0 + (unsigned)s * (CH * NS * 4);
        const unsigned db = db0 + (unsigned)s * 256;

        f32x2 kA[4], kB[4]; unsigned qA[4], qB[4]; float vA[4], vB[4];
        f32x4 dA, dB;

#define LDG(KK, QQ, VV, DV, g)                                          \
        KK[0] = dsr64f<((g) * 4 + 0) * 128>(kb);                        \
        KK[1] = dsr64f<((g) * 4 + 1) * 128>(kb);                        \
        KK[2] = dsr64f<((g) * 4 + 2) * 128>(kb);                        \
        KK[3] = dsr64f<((g) * 4 + 3) * 128>(kb);                        \
        QQ[0] = dsr32u<((g) * 4 + 0) * 64>(qb);                         \
        QQ[1] = dsr32u<((g) * 4 + 1) * 64>(qb);                         \
        QQ[2] = dsr32u<((g) * 4 + 2) * 64>(qb);                         \
        QQ[3] = dsr32u<((g) * 4 + 3) * 64>(qb);                         \
        VV[0] = dsr32f<((g) * 4 + 0) * 128>(vb);                        \
        VV[1] = dsr32f<((g) * 4 + 1) * 128>(vb);                        \
        VV[2] = dsr32f<((g) * 4 + 2) * 128>(vb);                        \
        VV[3] = dsr32f<((g) * 4 + 3) * 128>(vb);                        \
        DV    = dsr128<(g) * 16>(db);          /* broadcast: 4 decays */

#define CMP(KK, QQ, VV, DV, g)                                          \
        {                                                               \
            _Pragma("unroll")                                           \
            for (int p = 0; p < 4; ++p) {                               \
                float k0 = KK[p][0], k1 = KK[p][1];                     \
                float q0 = h2f((unsigned short)(QQ[p] & 0xffff));       \
                float q1 = h2f((unsigned short)(QQ[p] >> 16));          \
                float vj = VV[p];                                       \
                float d  = DV[p];                                       \
                float xr = fmaf(k1, s1, k0 * s0);                       \
                f32x2 rd = dpp_sum16x2(xr, o_pend);                     \
                if (ii == 0) {                                          \
                    if ((g) == 0 && p == 0) {                           \
                        if (c > 0) obuf[(c + 3) & 3][CH - 1][col] = f2h(rd[1]); \
                    } else {                                            \
                        obuf[s][(g) * 4 + p - 1][col] = f2h(rd[1]);     \
                    }                                                   \
                }                                                       \
                float delta = vj - rd[0];                               \
                float a0 = fmaf(d, s0, k0 * delta);                     \
                float a1 = fmaf(d, s1, k1 * delta);                     \
                s0 += tanh_fast(a0); s1 += tanh_fast(a1);               \
                o_pend = fmaf(q1, s1, q0 * s0);                         \
            }                                                           \
        }

        // 8-group pipeline: asm ds_reads can't be sunk; lgkmcnt(13) = wait
        // group done while next group's 13 DS ops stay in flight.
        LDG(kA, qA, vA, dA, 0);
        LDG(kB, qB, vB, dB, 1);
        LGKM(13); SB;
        CMP(kA, qA, vA, dA, 0);
        LDG(kA, qA, vA, dA, 2);
        LGKM(13); SB;
        CMP(kB, qB, vB, dB, 1);
        LDG(kB, qB, vB, dB, 3);
        LGKM(13); SB;
        CMP(kA, qA, vA, dA, 2);
        LDG(kA, qA, vA, dA, 4);
        LGKM(13); SB;
        CMP(kB, qB, vB, dB, 3);
        LDG(kB, qB, vB, dB, 5);
        LGKM(13); SB;
        CMP(kA, qA, vA, dA, 4);
        LDG(kA, qA, vA, dA, 6);
        LGKM(13); SB;
        CMP(kB, qB, vB, dB, 5);
        LDG(kB, qB, vB, dB, 7);
        LGKM(13); SB;
        CMP(kA, qA, vA, dA, 6);
        LGKM(0); SB;
        CMP(kB, qB, vB, dB, 7);
#undef LDG
#undef CMP
    }

    // Final pending o (t = T_LEN-1) -> last slot, then flush last two chunks.
    {
        float oo = dpp_sum16(o_pend);
        if (ii == 0) obuf[(NCHUNK - 1) & 3][CH - 1][col] = f2h(oo);
    }
    __builtin_amdgcn_s_barrier();
    if (wave == 6) { flush(NCHUNK - 2); flush(NCHUNK - 1); }

    float* so = Sout + (size_t)bh * NS * NS;
    so[(i0 + 0) * NS + col] = s0;
    so[(i0 + 1) * NS + col] = s1;
}

// ---------------------------------------------------------------------------
extern "C" void kernel_launch(void* const* d_in, const int* in_sizes, int n_in,
                              void* d_out, int out_size, void* d_ws, size_t ws_size,
                              hipStream_t stream) {
    const float* x       = (const float*)d_in[0];
    const float* S0      = (const float*)d_in[1];
    const float* Wq      = (const float*)d_in[2];
    const float* Wk      = (const float*)d_in[3];
    const float* Wv      = (const float*)d_in[4];
    const float* Wa      = (const float*)d_in[5];
    const float* A_log   = (const float*)d_in[6];
    const float* dt_bias = (const float*)d_in[7];
    const float* Wout    = (const float*)d_in[8];

    float* out  = (float*)d_out;
    float* Sout = out + (size_t)T_LEN * BB * DIM;

    // --- workspace layout (~171 MB peak) ---
    char* w = (char*)d_ws;
    auto alloc = [&](size_t bytes) {
        char* p = w; w += (bytes + 255) & ~(size_t)255; return p;
    };
    unsigned short* xh    = (unsigned short*)alloc((size_t)MROWS * DIM * 2); // 16.8 MB
    unsigned short* xl    = (unsigned short*)alloc((size_t)MROWS * DIM * 2); // 16.8 MB
    unsigned short* Wkh   = (unsigned short*)alloc((size_t)KD * DIM * 2);    // 3.67 MB
    unsigned short* Wkl   = (unsigned short*)alloc((size_t)KD * DIM * 2);    // 3.67 MB
    unsigned short* Wvh   = (unsigned short*)alloc((size_t)KD * DIM * 2);    // 3.67 MB
    unsigned short* Wvl   = (unsigned short*)alloc((size_t)KD * DIM * 2);    // 3.67 MB
    unsigned short* Wah   = (unsigned short*)alloc((size_t)HH * DIM * 2);    // 0.11 MB
    unsigned short* Wal   = (unsigned short*)alloc((size_t)HH * DIM * 2);    // 0.11 MB
    unsigned short* Wqh16 = (unsigned short*)alloc((size_t)KD * DIM * 2);    // 3.67 MB
    float* kf             = (float*)alloc((size_t)MROWS * KD * 4);           // 58.7 MB
    float* vf             = (float*)alloc((size_t)MROWS * KD * 4);           // 58.7 MB
    unsigned short* Woh   = (unsigned short*)alloc((size_t)DIM * KD * 2);    // 3.67 MB
    // Aliases: Sq (fp16) over xh/xl (x dead after kv-proj);
    //          x-fp16 over vf head (dead once v tiles of kv-proj run,
    //          which happens after q-gemm).
    unsigned short* Sq   = xh;
    unsigned short* xf16 = (unsigned short*)vf;

    // --- d_out head as scratch for q (fp16) + decay: dead before out GEMM ---
    unsigned short* qh  = (unsigned short*)d_out;                 // 29.36 MB
    float* decayb       = (float*)((char*)d_out + (size_t)MROWS * KD * 2); // 1.83 MB

    // 1) all casts in one launch
    {
        int items = MEGACAST_ITEMS;
        megacast_kernel<<<(items + 255) / 256, 256, 0, stream>>>(
            x, xh, xl, xf16, Wk, Wkh, Wkl, Wv, Wvh, Wvl,
            Wa, Wah, Wal, Wq, Wqh16, Wout, Woh);
    }
    // 2) q projection (fp16 MFMA, fused l2norm) -- must precede kv (xf16 alias)
    q_gemm_f16_kernel<<<dim3(14, 64), 256, 0, stream>>>(xf16, Wqh16, qh);
    // 3) fused k (norm) + decay + v projection
    kv_proj_kernel<<<dim3(29, 64), 256, 0, stream>>>(
        xh, xl, Wkh, Wkl, Wvh, Wvl, Wah, Wal, A_log, dt_bias, kf, vf, decayb);
    // 4) scan
    scan_kernel<<<BB * HH, 512, 0, stream>>>(kf, qh, vf, decayb, S0, Sq, Sout);
    // 5) output GEMM
    out_gemm_kernel<<<dim3(8, 64), 256, 0, stream>>>(Sq, Woh, out);
}